// Round 1
// baseline (820.661 us; speedup 1.0000x reference)
//
#include <hip/hip_runtime.h>

// Fused KV-cache beam reorder + suffix append.
// k_buf,v_buf: [L=8, G=128, NH=8, T=128, HD=64] fp32
// k_new,v_new: [L, G, NH, 1, HD] fp32
// new_beam_idx: [G] int32, pos: scalar int32 (device, 1-elem)
// out = concat(k_out, v_out) flat.
//
// Vec4 index layout per tensor (all pow2):
//   hd4: bits 0-3 (HD/4=16), t: bits 4-10 (T=128), h: bits 11-13 (NH=8),
//   g: bits 14-20 (G=128), l: bits 21-23 (L=8).  NV = 2^24 vec4 per tensor.

__global__ __launch_bounds__(256) void kv_reorder_append(
    const float4* __restrict__ k_buf,
    const float4* __restrict__ v_buf,
    const float4* __restrict__ k_new,
    const float4* __restrict__ v_new,
    const int*    __restrict__ beam_idx,
    const int*    __restrict__ pos_ptr,
    float4*       __restrict__ out,
    unsigned total_vec)  // 2 * NV = 2^25
{
    const unsigned pos = (unsigned)*pos_ptr;
    const unsigned stride = gridDim.x * blockDim.x;
    for (unsigned i = blockIdx.x * blockDim.x + threadIdx.x; i < total_vec; i += stride) {
        const unsigned tensor = i >> 24;           // 0 = k, 1 = v
        const unsigned iv     = i & 0x00FFFFFFu;   // index within tensor
        const unsigned hd4 = iv & 15u;
        const unsigned t   = (iv >> 4) & 127u;
        const unsigned g   = (iv >> 14) & 127u;

        const float4* __restrict__ src;
        unsigned src_iv;
        if (t == pos) {
            // new token: k_new[l, g, h, 0, hd]  (indexed by OUTPUT beam g)
            const unsigned lgh = iv >> 11;         // (l*G + g)*NH + h
            src_iv = (lgh << 4) | hd4;
            src = tensor ? v_new : k_new;
        } else {
            // gathered copy: buf[l, beam_idx[g], h, t, hd]
            const unsigned sg = (unsigned)beam_idx[g];
            src_iv = iv + ((sg - g) << 14);        // mod-2^32 arithmetic; result is valid index
            src = tensor ? v_buf : k_buf;
        }
        out[i] = src[src_iv];
    }
}

extern "C" void kernel_launch(void* const* d_in, const int* in_sizes, int n_in,
                              void* d_out, int out_size, void* d_ws, size_t ws_size,
                              hipStream_t stream) {
    const float4* k_buf = (const float4*)d_in[0];
    const float4* v_buf = (const float4*)d_in[1];
    const float4* k_new = (const float4*)d_in[2];
    const float4* v_new = (const float4*)d_in[3];
    const int*    bidx  = (const int*)d_in[4];
    const int*    pos   = (const int*)d_in[5];
    float4*       out   = (float4*)d_out;

    const unsigned total_vec = 1u << 25;  // 2 tensors * 2^24 vec4
    const int block = 256;
    const int grid  = 16384;              // grid-stride: 8 vec4 per thread
    kv_reorder_append<<<grid, block, 0, stream>>>(k_buf, v_buf, k_new, v_new,
                                                  bidx, pos, out, total_vec);
}